// Round 18
// baseline (140.218 us; speedup 1.0000x reference)
//
#include <hip/hip_runtime.h>
#include <math.h>

// DTM weighted-quantile kernel, v6: 4-ary multi-threshold bisection.
// Evidence: v1 82.4 (31 trips, 97% busy); v2 79.5 (~15 trips, 75%);
// v3 Illinois 90.9 (serial tail up); v4 dual-output 120.6 (occupancy crash);
// v5 DPP 74.0 (80% busy, VGPR 40). Work cuts and per-trip latency cuts both
// gave only single-digit %: the floor is the SERIAL ROUND-TRIP COUNT.
// v6: each pass probes 3 thresholds (quartiles of the bracket) with three
// independent count accumulators and hand-interleaved DPP reduce chains ->
// bracket shrinks 4x per round trip: ~15 trips -> ~9.

#define M_POINTS 2048
#define PER_LANE 32  // M_POINTS / 64
#define M0 0.3f

// ---- DPP primitives (row_shr:N = 0x110|N, row_bcast:15 = 0x142, :31 = 0x143)
template<int CTRL>
__device__ __forceinline__ float dpp_add_step(float x) {
    union { int i; float f; } u, r;
    u.f = x;
    r.i = __builtin_amdgcn_update_dpp(0, u.i, CTRL, 0xf, 0xf, true); // 0-fill
    return x + r.f;
}
template<int CTRL>
__device__ __forceinline__ float dpp_max_step(float x) {   // valid for x >= 0
    union { int i; float f; } u, r;
    u.f = x;
    r.i = __builtin_amdgcn_update_dpp(0, u.i, CTRL, 0xf, 0xf, true);
    return fmaxf(x, r.f);
}
template<int CTRL>
__device__ __forceinline__ float dpp_min_step(float x) {
    union { int i; float f; } u, r;
    u.f = x;
    r.i = __builtin_amdgcn_update_dpp(0x7F800000, u.i, CTRL, 0xf, 0xf, false);
    return fminf(x, r.f);
}
__device__ __forceinline__ float lane63(float x) {
    union { int i; float f; } u;
    u.f = x;
    u.i = __builtin_amdgcn_readlane(u.i, 63);
    return u.f;                                   // wave-uniform (SGPR)
}
__device__ __forceinline__ float wave_reduce_sum(float x) {
    x = dpp_add_step<0x111>(x); x = dpp_add_step<0x112>(x);
    x = dpp_add_step<0x114>(x); x = dpp_add_step<0x118>(x);
    x = dpp_add_step<0x142>(x); x = dpp_add_step<0x143>(x);
    return lane63(x);
}
__device__ __forceinline__ float wave_reduce_max(float x) {
    x = dpp_max_step<0x111>(x); x = dpp_max_step<0x112>(x);
    x = dpp_max_step<0x114>(x); x = dpp_max_step<0x118>(x);
    x = dpp_max_step<0x142>(x); x = dpp_max_step<0x143>(x);
    return lane63(x);
}
__device__ __forceinline__ float wave_reduce_min(float x) {
    x = dpp_min_step<0x111>(x); x = dpp_min_step<0x112>(x);
    x = dpp_min_step<0x114>(x); x = dpp_min_step<0x118>(x);
    x = dpp_min_step<0x142>(x); x = dpp_min_step<0x143>(x);
    return lane63(x);
}
// Three independent sums, chains explicitly interleaved -> latency ~ one chain.
__device__ __forceinline__ void wave_reduce_sum3(float& a, float& b, float& c) {
    a = dpp_add_step<0x111>(a); b = dpp_add_step<0x111>(b); c = dpp_add_step<0x111>(c);
    a = dpp_add_step<0x112>(a); b = dpp_add_step<0x112>(b); c = dpp_add_step<0x112>(c);
    a = dpp_add_step<0x114>(a); b = dpp_add_step<0x114>(b); c = dpp_add_step<0x114>(c);
    a = dpp_add_step<0x118>(a); b = dpp_add_step<0x118>(b); c = dpp_add_step<0x118>(c);
    a = dpp_add_step<0x142>(a); b = dpp_add_step<0x142>(b); c = dpp_add_step<0x142>(c);
    a = dpp_add_step<0x143>(a); b = dpp_add_step<0x143>(b); c = dpp_add_step<0x143>(c);
    a = lane63(a); b = lane63(b); c = lane63(c);
}

__global__ __launch_bounds__(256) void dtm_kernel(
    const float* __restrict__ inputs,   // [B, M, 2]
    const float* __restrict__ weight,   // [B, M]
    const float* __restrict__ grid,     // [N, 2]
    float* __restrict__ out,            // [B, N]  (f32)
    int B, int N)
{
    const int lane = threadIdx.x & 63;
    const int gwave = blockIdx.x * (blockDim.x >> 6) + (threadIdx.x >> 6);
    if (gwave >= B * N) return;           // wave-uniform exit
    const int b = gwave / N;
    const int n = gwave - b * N;

    const float gx = grid[2 * n];
    const float gy = grid[2 * n + 1];

    const float* __restrict__ inb = inputs + (size_t)b * M_POINTS * 2;
    const float* __restrict__ wb  = weight + (size_t)b * M_POINTS;

    // Contiguous 32 elements per lane -> float4 staging.
    const int base = lane * PER_LANE;
    const float4* __restrict__ xyv = reinterpret_cast<const float4*>(inb + 2 * base);
    const float4* __restrict__ wv  = reinterpret_cast<const float4*>(wb + base);

    float d2[PER_LANE], w[PER_LANE];
    float wsum_local = 0.0f, vmax_local = 0.0f;
    #pragma unroll
    for (int q = 0; q < PER_LANE / 4; ++q) {
        const float4 wq = wv[q];
        const float4 a  = xyv[2 * q];       // x0 y0 x1 y1
        const float4 c4 = xyv[2 * q + 1];   // x2 y2 x3 y3
        float dx, dy;
        dx = a.x  - gx; dy = a.y  - gy; d2[4*q+0] = fmaf(dx, dx, dy * dy);
        dx = a.z  - gx; dy = a.w  - gy; d2[4*q+1] = fmaf(dx, dx, dy * dy);
        dx = c4.x - gx; dy = c4.y - gy; d2[4*q+2] = fmaf(dx, dx, dy * dy);
        dx = c4.z - gx; dy = c4.w - gy; d2[4*q+3] = fmaf(dx, dx, dy * dy);
        w[4*q+0] = wq.x; w[4*q+1] = wq.y; w[4*q+2] = wq.z; w[4*q+3] = wq.w;
        wsum_local += wq.x + wq.y + wq.z + wq.w;
        vmax_local = fmaxf(vmax_local, fmaxf(fmaxf(d2[4*q+0], d2[4*q+1]),
                                             fmaxf(d2[4*q+2], d2[4*q+3])));
    }
    const float total = wave_reduce_sum(wsum_local);
    const float vmax  = wave_reduce_max(vmax_local);   // overlaps with sum chain
    const float bound = M0 * total;

    // Phase 1: 4-ary bisection. Invariant: wlo=cnt(vlo) < bound <= whi=cnt(vhi).
    float vlo = 0.0f, wlo = 0.0f;
    float vhi = vmax, whi = total;
    #pragma unroll 1
    for (int pass = 0; pass < 24; ++pass) {
        if (whi - wlo <= 0.75f) break;                 // ~<=2 elements remain
        const float qt = 0.25f * (vhi - vlo);
        const float t1 = vlo + qt, t2 = vlo + 2.0f * qt, t3 = vlo + 3.0f * qt;
        if (!(t1 > vlo && t1 < t2 && t2 < t3 && t3 < vhi)) break; // degenerate
        float c1 = 0.0f, c2 = 0.0f, c3 = 0.0f;
        #pragma unroll
        for (int j = 0; j < PER_LANE; ++j) {
            c1 += (d2[j] <= t1) ? w[j] : 0.0f;
            c2 += (d2[j] <= t2) ? w[j] : 0.0f;
            c3 += (d2[j] <= t3) ? w[j] : 0.0f;
        }
        wave_reduce_sum3(c1, c2, c3);
        // Scalar 4-way bracket update (c1 <= c2 <= c3 by construction).
        if (c1 >= bound)      { vhi = t1; whi = c1; }
        else if (c2 >= bound) { vlo = t1; wlo = c1; vhi = t2; whi = c2; }
        else if (c3 >= bound) { vlo = t2; wlo = c2; vhi = t3; whi = c3; }
        else                  { vlo = t3; wlo = c3; }
    }

    // Phase 2: exact extraction - ascending distinct values above vlo.
    float r2 = vhi, W = wlo;
    #pragma unroll 1
    for (int step = 0; step < 64; ++step) {
        float m = __builtin_inff();
        #pragma unroll
        for (int j = 0; j < PER_LANE; ++j)
            m = fminf(m, (d2[j] > vlo) ? d2[j] : __builtin_inff());
        m = wave_reduce_min(m);                      // smallest value > vlo
        float c = 0.0f;
        #pragma unroll
        for (int j = 0; j < PER_LANE; ++j)
            c += (d2[j] <= m) ? w[j] : 0.0f;
        c = wave_reduce_sum(c);
        if (c >= bound) { r2 = m; W = wlo; break; }  // wlo = cnt(values < m)
        vlo = m; wlo = c;
    }

    // Phase 3: S = sum_{d2 < r2} w*d2.
    float S = 0.0f;
    #pragma unroll
    for (int j = 0; j < PER_LANE; ++j)
        if (d2[j] < r2) S = fmaf(w[j], d2[j], S);
    S = wave_reduce_sum(S);

    const float margin = fmaxf(bound - W, 0.0f);     // clamp FP-noise sign flip
    const float val = fmaxf(fmaf(r2, margin, S), 0.0f);
    if (lane == 0) out[gwave] = sqrtf(val / bound);
}

extern "C" void kernel_launch(void* const* d_in, const int* in_sizes, int n_in,
                              void* d_out, int out_size, void* d_ws, size_t ws_size,
                              hipStream_t stream) {
    const float* inputs = (const float*)d_in[0];   // [B, M, 2]
    const float* weight = (const float*)d_in[1];   // [B, M]
    const float* grid   = (const float*)d_in[2];   // [N, 2]
    float* out = (float*)d_out;                    // [B, N] f32

    const int N = in_sizes[2] / 2;                 // 6561
    const int B = out_size / N;                    // 2
    // M hard-wired to 2048 (PER_LANE*64).

    const int total_waves = B * N;                 // 13122
    const int waves_per_block = 256 / 64;
    const int blocks = (total_waves + waves_per_block - 1) / waves_per_block;

    dtm_kernel<<<blocks, 256, 0, stream>>>(inputs, weight, grid, out, B, N);
}